// Round 1
// baseline (205.882 us; speedup 1.0000x reference)
//
#include <hip/hip_runtime.h>

// Fused: per-channel affine+relu -> dilated(2) 3x3 box-sum (zero pad) ->
// sigmoid gate -> multiply -> 2x nearest upsample -> add y.
//
// Mapping: 1 thread = 2 adjacent input pixels (w0, w0+1) -> 4x2 output block.
// Lanes stride 16 B on y/out so every float4 load/store instruction is fully
// contiguous across the wave (R4 post-mortem: 8-pixel strips made each
// y/out dwordx4 instruction touch 64 cache lines instead of 16 -> VMEM
// request-bound at 2.5 TB/s).
// x taps: 3 float2 loads per row (w0-2..w0+3), UNCONDITIONAL with clamped
// addresses (no exec-mask branches; R3 post-mortem), masked arithmetically
// post-relu. Plain cached stores (nt caused 2.5x write amplification).
//
// R5: XCD-chunked block swizzle. Default round-robin puts blocks h-2/h/h+2
// (which share x rows) on 3 different XCDs -> each x line fetched into 3
// non-coherent L2s (~50 MB extra L3->L2 fabric traffic). Chunking gives each
// XCD 1536 consecutive blocks = 3 whole (b,c) images, so all vertical x reuse
// is same-XCD L2-local. 12288 % 8 == 0 -> bijective.

#define DIA 2

__global__ __launch_bounds__(256) void fused_kernel(
    const float* __restrict__ x, const float* __restrict__ y,
    const float* __restrict__ w1v, const float* __restrict__ b1v,
    const float* __restrict__ w2v, const float* __restrict__ b2v,
    float* __restrict__ out)
{
    constexpr int C = 3, H = 512, W = 512, W2 = 1024;
    constexpr int NBLK = 12288, CHUNK = NBLK / 8;

    // XCD-aware swizzle: hardware assigns consecutive blockIdx round-robin
    // across 8 XCDs; remap so each XCD owns a contiguous logical chunk.
    int g = blockIdx.x;
    int l = (g & 7) * CHUNK + (g >> 3);

    int idx = l * 256 + threadIdx.x;
    int wp = idx & (W / 2 - 1);                              // 0..255, lane-contiguous
    int h  = __builtin_amdgcn_readfirstlane((idx >> 8) & (H - 1));
    int bc = __builtin_amdgcn_readfirstlane(idx >> 17);      // 0..23 (b*C + c)
    int c  = bc % C;
    int w0 = wp * 2;                                         // even, 0..510

    const float s_w1 = w1v[c], s_b1 = b1v[c];
    const float s_w2 = w2v[c], s_b2 = b2v[c];

    const float* __restrict__ xrow = x + ((size_t)bc * H + (size_t)h) * W;

    const bool ok0 = (h >= DIA), ok2 = (h < H - DIA);
    const bool lok = (w0 > 0), rok = (w0 + 2 < W);
    const float m0 = ok0 ? 1.f : 0.f;
    const float m2 = ok2 ? 1.f : 0.f;
    const float mL = lok ? 1.f : 0.f;
    const float mR = rok ? 1.f : 0.f;

    // Clamped, always-in-bounds addresses (8B-aligned: offsets all even).
    const float* r1 = xrow;
    const float* r0 = ok0 ? (xrow - DIA * W) : xrow;
    const float* r2 = ok2 ? (xrow + DIA * W) : xrow;
    const int wl = lok ? (w0 - 2) : w0;
    const int wr = rok ? (w0 + 2) : w0;

    // ---- issue ALL global loads up front, unconditionally ----
    float2 L0 = *(const float2*)(r0 + wl);
    float2 M0 = *(const float2*)(r0 + w0);
    float2 R0 = *(const float2*)(r0 + wr);
    float2 L1 = *(const float2*)(r1 + wl);
    float2 M1 = *(const float2*)(r1 + w0);
    float2 R1 = *(const float2*)(r1 + wr);
    float2 L2 = *(const float2*)(r2 + wl);
    float2 M2 = *(const float2*)(r2 + w0);
    float2 R2 = *(const float2*)(r2 + wr);

    size_t obase = (((size_t)bc * (2 * H) + (size_t)(2 * h)) * W2) + (size_t)(2 * w0);
    float4 ya = *(const float4*)(y + obase);
    float4 yb = *(const float4*)(y + obase + W2);

    // ---- compute ----
    auto act = [&](float v) { return fmaxf(fmaf(v, s_w1, s_b1), 0.f); };

    // center (= x_r): always valid
    float xo0 = act(M1.x);
    float xo1 = act(M1.y);

    float sum0 = mL * act(L1.x) + xo0 + mR * act(R1.x);
    float sum1 = mL * act(L1.y) + xo1 + mR * act(R1.y);
    sum0 += m0 * (mL * act(L0.x) + act(M0.x) + mR * act(R0.x));
    sum1 += m0 * (mL * act(L0.y) + act(M0.y) + mR * act(R0.y));
    sum0 += m2 * (mL * act(L2.x) + act(M2.x) + mR * act(R2.x));
    sum1 += m2 * (mL * act(L2.y) + act(M2.y) + mR * act(R2.y));

    float z0 = fmaf(sum0, s_w2, s_b2);
    float z1 = fmaf(sum1, s_w2, s_b2);
    float o0 = xo0 / (1.f + __expf(-z0));
    float o1 = xo1 / (1.f + __expf(-z1));

    // ---- 2x nearest upsample + add y (lane-contiguous float4 stores) ----
    *(float4*)(out + obase)      = make_float4(ya.x + o0, ya.y + o0, ya.z + o1, ya.w + o1);
    *(float4*)(out + obase + W2) = make_float4(yb.x + o0, yb.y + o0, yb.z + o1, yb.w + o1);
}

extern "C" void kernel_launch(void* const* d_in, const int* in_sizes, int n_in,
                              void* d_out, int out_size, void* d_ws, size_t ws_size,
                              hipStream_t stream) {
    const float* x  = (const float*)d_in[0];
    const float* y  = (const float*)d_in[1];
    const float* w1 = (const float*)d_in[2];
    const float* b1 = (const float*)d_in[3];
    const float* w2 = (const float*)d_in[4];
    const float* b2 = (const float*)d_in[5];
    float* out = (float*)d_out;

    constexpr int B = 8, C = 3, H = 512, W = 512;
    int total_threads = B * C * H * (W / 2);   // 3,145,728
    int block = 256;
    int grid  = total_threads / block;         // 12,288
    fused_kernel<<<grid, block, 0, stream>>>(x, y, w1, b1, w2, b2, out);
}